// Round 6
// baseline (557.224 us; speedup 1.0000x reference)
//
#include <hip/hip_runtime.h>
#include <math.h>

#define B_ 2
#define S_ 1024
#define D_ 512
#define N_ 4096
#define H_ 8
#define DH_ 64
#define NCAND 288   // 9 neighbor cells * 32 entries
#define TOPK 32
#define NTOK (B_*S_)   // 2048
#define NGROUPS 768    // max same-cell groups of <=4 tokens

#define NROWS 16384       // B*H*S
#define NSLOT_BH 8704     // sum over rows i<1024 of (i/64+1)
#define NSLOTS (16*NSLOT_BH)

__device__ __forceinline__ float wave_sum(float v) {
    #pragma unroll
    for (int o = 32; o; o >>= 1) v += __shfl_xor(v, o);
    return v;
}
__device__ __forceinline__ float wave_max(float v) {
    #pragma unroll
    for (int o = 32; o; o >>= 1) v = fmaxf(v, __shfl_xor(v, o));
    return v;
}

// ---------- token sort by spatial cell + same-cell group descriptors ----------
__global__ __launch_bounds__(1024) void sort_tokens_kernel(
    const float* __restrict__ qk_pos, const float* __restrict__ v_pos,
    const float* __restrict__ pos_min, const float* __restrict__ pos_range,
    int* __restrict__ order_qk, int* __restrict__ order_v,
    int2* __restrict__ desc_qk, int2* __restrict__ desc_v)
{
    __shared__ int hist[256], tmp[256], offs[256], startc[256], gcnt[256];
    const int t = threadIdx.x;
    const float pm0 = pos_min[0], pm1 = pos_min[1];
    const float pr0 = pos_range[0], pr1 = pos_range[1];
    for (int pass = 0; pass < 2; pass++) {
        const float* pos = pass ? v_pos : qk_pos;
        int* order = pass ? order_v : order_qk;
        int2* desc = pass ? desc_v : desc_qk;
        if (t < NGROUPS) desc[t] = make_int2(0, 0);
        if (t < 256) hist[t] = 0;
        __syncthreads();
        int cell[2];
        #pragma unroll
        for (int k = 0; k < 2; k++) {
            int tok = t + k * 1024;
            float p0 = pos[tok * 2], p1 = pos[tok * 2 + 1];
            int cx = min(max((int)((p0 - pm0) / pr0 * 16.f), 0), 15);
            int cy = min(max((int)((p1 - pm1) / pr1 * 16.f), 0), 15);
            cell[k] = cx * 16 + cy;
            atomicAdd(&hist[cell[k]], 1);
        }
        __syncthreads();
        if (t < 256) tmp[t] = hist[t];
        __syncthreads();
        for (int d = 1; d < 256; d <<= 1) {
            int v = 0;
            if (t < 256 && t >= d) v = tmp[t - d];
            __syncthreads();
            if (t < 256) tmp[t] += v;
            __syncthreads();
        }
        if (t < 256) {
            startc[t] = tmp[t] - hist[t];
            offs[t]   = startc[t];
            gcnt[t]   = (hist[t] + 3) >> 2;
        }
        __syncthreads();
        #pragma unroll
        for (int k = 0; k < 2; k++) {
            int tok = t + k * 1024;
            int p = atomicAdd(&offs[cell[k]], 1);
            order[p] = tok;
        }
        __syncthreads();
        if (t < 256) tmp[t] = gcnt[t];
        __syncthreads();
        for (int d = 1; d < 256; d <<= 1) {
            int v = 0;
            if (t < 256 && t >= d) v = tmp[t - d];
            __syncthreads();
            if (t < 256) tmp[t] += v;
            __syncthreads();
        }
        if (t < 256) {
            int g0 = tmp[t] - gcnt[t];
            for (int k = 0; k < gcnt[t]; k++)
                desc[g0 + k] = make_int2(startc[t] + 4 * k, min(4, hist[t] - 4 * k));
        }
        __syncthreads();
    }
}

// ---------- QK kernel: one block per <=4-token same-cell group ----------
// Shared dot phase (each neuron row loaded once, 4 dots); then wave w owns
// token w end-to-end: ballot rank (wave-uniform count), gates, pos-loss,
// accumulate — wave-level reductions only, no block barriers.
__global__ __launch_bounds__(256, 3) void qk_kernel(
    const int2* __restrict__ desc, const int* __restrict__ order,
    const float* __restrict__ x, const float* __restrict__ qk_pos,
    const float* __restrict__ tauQ, const float* __restrict__ tauK,
    const float* __restrict__ neurons, const float* __restrict__ npos,
    const int* __restrict__ cmap,
    const float* __restrict__ pos_min, const float* __restrict__ pos_range,
    float* __restrict__ Q, float* __restrict__ K, float* __restrict__ posacc)
{
    const int gid = (blockIdx.x & 7) * 96 + (blockIdx.x >> 3);  // XCD-local groups
    const int2 dsc = desc[gid];
    const int gstart = dsc.x, count = dsc.y;
    if (count == 0) return;

    __shared__ int   idx[NCAND];
    __shared__ float msk[NCAND];
    __shared__ float act[4][NCAND];
    __shared__ int   ce[4][NCAND];       // kept slots (tie-safe sizing)
    __shared__ float cwq[4][NCAND], cwk[4][NCAND];
    __shared__ int   toks[4];

    const int t = threadIdx.x, wid = t >> 6, lane = t & 63;
    if (t < 4) toks[t] = order[gstart + min(t, count - 1)];
    __syncthreads();
    const int token0 = toks[0];

    const float pm0 = pos_min[0], pm1 = pos_min[1];
    const float pr0 = pos_range[0], pr1 = pos_range[1];
    {
        const float p0 = qk_pos[token0 * 2], p1 = qk_pos[token0 * 2 + 1];
        const int cx = min(max((int)((p0 - pm0) / pr0 * 16.f), 0), 15);
        const int cy = min(max((int)((p1 - pm1) / pr1 * 16.f), 0), 15);
        for (int c = t; c < NCAND; c += 256) {
            int o = c >> 5, ms = c & 31;
            int nx = min(max(cx + o / 3 - 1, 0), 15), ny = min(max(cy + o % 3 - 1, 0), 15);
            int cand = cmap[(nx * 16 + ny) * 32 + ms];
            idx[c] = cand >= 0 ? cand : 0;
            msk[c] = cand >= 0 ? 1.f : 0.f;
        }
    }
    __syncthreads();

    // x fragments for up to 4 tokens (dupes of token0 beyond count)
    float4 xa[4], xb[4];
    #pragma unroll
    for (int tk = 0; tk < 4; tk++) {
        const float4* xp = (const float4*)(x + (size_t)toks[tk] * D_);
        xa[tk] = xp[lane * 2]; xb[tk] = xp[lane * 2 + 1];
    }

    // shared dots: wave-per-candidate, row loaded once, count dots
    #pragma unroll 2
    for (int c = wid * 72; c < wid * 72 + 72; ++c) {
        const float4* r4 = (const float4*)(neurons + (size_t)idx[c] * D_);
        const float4 ra = r4[lane * 2], rb = r4[lane * 2 + 1];
        const float mv = msk[c];
        #pragma unroll
        for (int tk = 0; tk < 4; tk++) {
            if (tk < count) {   // block-uniform
                float a = xa[tk].x * ra.x + xa[tk].y * ra.y + xa[tk].z * ra.z + xa[tk].w * ra.w
                        + xb[tk].x * rb.x + xb[tk].y * rb.y + xb[tk].z * rb.z + xb[tk].w * rb.w;
                #pragma unroll
                for (int o = 32; o; o >>= 1) a += __shfl_xor(a, o);
                if (lane == 0) act[tk][c] = (mv != 0.f) ? a : -1e9f;
            }
        }
    }
    __syncthreads();

    if (wid >= count) return;           // wave-uniform; no barriers below
    const int token = toks[wid];
    const float* actw = act[wid];
    int*   cew = ce[wid];
    float* wq  = cwq[wid];
    float* wk  = cwk[wid];

    // rank via ballot+popcount; keep iff #strictly-greater < TOPK (ties all kept)
    float ej[5];
    #pragma unroll
    for (int k = 0; k < 5; k++) {
        int j = lane + 64 * k;
        ej[k] = (j < NCAND) ? actw[j] : -1e30f;
    }
    int nk = 0;                          // wave-uniform (ballot is wave-wide)
    for (int e = 0; e < NCAND; e++) {
        float ev = actw[e];
        int cgt = 0;
        #pragma unroll
        for (int k = 0; k < 5; k++)
            cgt += __popcll(__ballot(ej[k] > ev));
        if (cgt < TOPK) {
            if (lane == 0) cew[nk] = e;
            nk++;
        }
    }
    const int n = nk;

    const float tq = tauQ[token], tkk = tauK[token];
    float sQ = 0.f, sK = 0.f, mQ = 0.f, mK = 0.f;
    for (int p = lane; p < n; p += 64) {
        float s = actw[cew[p]];
        float rq = s - tq;
        float gq = (rq > 0.f) ? rq : 1e-8f * __expf(rq);
        float egq = __expf(gq) - 1.f;
        float rk = s - tkk;
        float gk = (rk > 0.f) ? rk : 1e-8f * __expf(rk);
        float egk = __expf(gk) - 1.f;
        wq[p] = egq; wk[p] = egk;
        sQ += egq; sK += egk;
        mQ = fmaxf(mQ, egq); mK = fmaxf(mK, egk);
    }
    sQ = wave_sum(sQ); mQ = wave_max(mQ);
    sK = wave_sum(sK); mK = wave_max(mK);
    const float scQ = tanhf(mQ) / (sQ + 1e-8f);
    const float scK = tanhf(mK) / (sK + 1e-8f);

    float cm = 0.f;
    for (int c = lane; c < NCAND; c += 64) cm += msk[c];
    cm = wave_sum(cm);

    const float qp0 = qk_pos[token * 2], qp1 = qk_pos[token * 2 + 1];
    float plq = 0.f;
    for (int p = lane; p < n; p += 64) {
        int e = cew[p];
        int id = idx[e];
        float m = msk[e], a = actw[e];
        float gq = wq[p] * scQ;
        wq[p] = a * gq * m;
        wk[p] = a * wk[p] * scK * m;
        cew[p] = id;
        float d0 = qp0 - npos[id * 2], d1 = qp1 - npos[id * 2 + 1];
        plq += gq * (d0 * d0 + d1 * d1) * m;
    }
    plq = wave_sum(plq);
    if (lane == 0) {
        int chunk = (token & 1023) >> 7;
        atomicAdd(&posacc[chunk], plq);
        atomicAdd(&posacc[8 + chunk], cm);
    }

    // accumulate Q,K: lane owns dims lane*8..lane*8+8 (coalesced 2KB/row/wave)
    float aq[8], ak[8];
    #pragma unroll
    for (int k = 0; k < 8; k++) { aq[k] = 0.f; ak[k] = 0.f; }
    for (int p = 0; p < n; p++) {
        const float aw = wq[p], bw = wk[p];
        const float4* row = (const float4*)(neurons + (size_t)cew[p] * D_ + lane * 8);
        const float4 ra = row[0], rb = row[1];
        aq[0] += aw * ra.x; aq[1] += aw * ra.y; aq[2] += aw * ra.z; aq[3] += aw * ra.w;
        aq[4] += aw * rb.x; aq[5] += aw * rb.y; aq[6] += aw * rb.z; aq[7] += aw * rb.w;
        ak[0] += bw * ra.x; ak[1] += bw * ra.y; ak[2] += bw * ra.z; ak[3] += bw * ra.w;
        ak[4] += bw * rb.x; ak[5] += bw * rb.y; ak[6] += bw * rb.z; ak[7] += bw * rb.w;
    }
    {
        float* qo = Q + (size_t)token * D_ + lane * 8;
        float* ko = K + (size_t)token * D_ + lane * 8;
        float4 v;
        v.x = aq[0]; v.y = aq[1]; v.z = aq[2]; v.w = aq[3]; *(float4*)qo = v;
        v.x = aq[4]; v.y = aq[5]; v.z = aq[6]; v.w = aq[7]; *(float4*)(qo + 4) = v;
        v.x = ak[0]; v.y = ak[1]; v.z = ak[2]; v.w = ak[3]; *(float4*)ko = v;
        v.x = ak[4]; v.y = ak[5]; v.z = ak[6]; v.w = ak[7]; *(float4*)(ko + 4) = v;
    }
}

// ---------- V kernel (same structure, single gate) ----------
__global__ __launch_bounds__(256, 3) void v_kernel(
    const int2* __restrict__ desc, const int* __restrict__ order,
    const float* __restrict__ x, const float* __restrict__ v_pos,
    const float* __restrict__ tauV,
    const float* __restrict__ neurons, const float* __restrict__ npos,
    const int* __restrict__ cmap,
    const float* __restrict__ pos_min, const float* __restrict__ pos_range,
    float* __restrict__ V, float* __restrict__ posacc)
{
    const int gid = (blockIdx.x & 7) * 96 + (blockIdx.x >> 3);
    const int2 dsc = desc[gid];
    const int gstart = dsc.x, count = dsc.y;
    if (count == 0) return;

    __shared__ int   idx[NCAND];
    __shared__ float msk[NCAND];
    __shared__ float act[4][NCAND];
    __shared__ int   ce[4][NCAND];
    __shared__ float cwv[4][NCAND];
    __shared__ int   toks[4];

    const int t = threadIdx.x, wid = t >> 6, lane = t & 63;
    if (t < 4) toks[t] = order[gstart + min(t, count - 1)];
    __syncthreads();
    const int token0 = toks[0];

    const float pm0 = pos_min[0], pm1 = pos_min[1];
    const float pr0 = pos_range[0], pr1 = pos_range[1];
    {
        const float p0 = v_pos[token0 * 2], p1 = v_pos[token0 * 2 + 1];
        const int cx = min(max((int)((p0 - pm0) / pr0 * 16.f), 0), 15);
        const int cy = min(max((int)((p1 - pm1) / pr1 * 16.f), 0), 15);
        for (int c = t; c < NCAND; c += 256) {
            int o = c >> 5, ms = c & 31;
            int nx = min(max(cx + o / 3 - 1, 0), 15), ny = min(max(cy + o % 3 - 1, 0), 15);
            int cand = cmap[(nx * 16 + ny) * 32 + ms];
            idx[c] = cand >= 0 ? cand : 0;
            msk[c] = cand >= 0 ? 1.f : 0.f;
        }
    }
    __syncthreads();

    float4 xa[4], xb[4];
    #pragma unroll
    for (int tk = 0; tk < 4; tk++) {
        const float4* xp = (const float4*)(x + (size_t)toks[tk] * D_);
        xa[tk] = xp[lane * 2]; xb[tk] = xp[lane * 2 + 1];
    }

    #pragma unroll 2
    for (int c = wid * 72; c < wid * 72 + 72; ++c) {
        const float4* r4 = (const float4*)(neurons + (size_t)idx[c] * D_);
        const float4 ra = r4[lane * 2], rb = r4[lane * 2 + 1];
        const float mv = msk[c];
        #pragma unroll
        for (int tk = 0; tk < 4; tk++) {
            if (tk < count) {
                float a = xa[tk].x * ra.x + xa[tk].y * ra.y + xa[tk].z * ra.z + xa[tk].w * ra.w
                        + xb[tk].x * rb.x + xb[tk].y * rb.y + xb[tk].z * rb.z + xb[tk].w * rb.w;
                #pragma unroll
                for (int o = 32; o; o >>= 1) a += __shfl_xor(a, o);
                if (lane == 0) act[tk][c] = (mv != 0.f) ? a : -1e9f;
            }
        }
    }
    __syncthreads();

    if (wid >= count) return;
    const int token = toks[wid];
    const float* actw = act[wid];
    int*   cew = ce[wid];
    float* wv  = cwv[wid];

    float ej[5];
    #pragma unroll
    for (int k = 0; k < 5; k++) {
        int j = lane + 64 * k;
        ej[k] = (j < NCAND) ? actw[j] : -1e30f;
    }
    int nk = 0;
    for (int e = 0; e < NCAND; e++) {
        float ev = actw[e];
        int cgt = 0;
        #pragma unroll
        for (int k = 0; k < 5; k++)
            cgt += __popcll(__ballot(ej[k] > ev));
        if (cgt < TOPK) {
            if (lane == 0) cew[nk] = e;
            nk++;
        }
    }
    const int n = nk;

    const float tv = tauV[token];
    float sV = 0.f, mV = 0.f;
    for (int p = lane; p < n; p += 64) {
        float s = actw[cew[p]];
        float rv = s - tv;
        float gv = (rv > 0.f) ? rv : 1e-8f * __expf(rv);
        float egv = __expf(gv) - 1.f;
        wv[p] = egv;
        sV += egv; mV = fmaxf(mV, egv);
    }
    sV = wave_sum(sV); mV = wave_max(mV);
    const float scV = tanhf(mV) / (sV + 1e-8f);

    float cm = 0.f;
    for (int c = lane; c < NCAND; c += 64) cm += msk[c];
    cm = wave_sum(cm);

    const float vp0 = v_pos[token * 2], vp1 = v_pos[token * 2 + 1];
    float plv = 0.f;
    for (int p = lane; p < n; p += 64) {
        int e = cew[p];
        int id = idx[e];
        float m = msk[e], a = actw[e];
        float gv = wv[p] * scV;
        wv[p] = a * gv * m;
        cew[p] = id;
        float d0 = vp0 - npos[id * 2], d1 = vp1 - npos[id * 2 + 1];
        plv += gv * (d0 * d0 + d1 * d1) * m;
    }
    plv = wave_sum(plv);
    if (lane == 0) {
        int chunk = (token & 1023) >> 7;
        atomicAdd(&posacc[16 + chunk], plv);
        atomicAdd(&posacc[24 + chunk], cm);
    }

    float av[8];
    #pragma unroll
    for (int k = 0; k < 8; k++) av[k] = 0.f;
    for (int p = 0; p < n; p++) {
        const float aw = wv[p];
        const float4* row = (const float4*)(neurons + (size_t)cew[p] * D_ + lane * 8);
        const float4 ra = row[0], rb = row[1];
        av[0] += aw * ra.x; av[1] += aw * ra.y; av[2] += aw * ra.z; av[3] += aw * ra.w;
        av[4] += aw * rb.x; av[5] += aw * rb.y; av[6] += aw * rb.z; av[7] += aw * rb.w;
    }
    {
        float* vo = V + (size_t)token * D_ + lane * 8;
        float4 v;
        v.x = av[0]; v.y = av[1]; v.z = av[2]; v.w = av[3]; *(float4*)vo = v;
        v.x = av[4]; v.y = av[5]; v.z = av[6]; v.w = av[7]; *(float4*)(vo + 4) = v;
    }
}

// ---------- attention partials (unchanged from R5) ----------
__global__ __launch_bounds__(128) void attn_partial_kernel(
    const float* __restrict__ Q, const float* __restrict__ K,
    const float* __restrict__ V,
    float* __restrict__ pm, float* __restrict__ pl, float* __restrict__ po)
{
    const int xx = blockIdx.x & 7;
    int k = blockIdx.x >> 3;             // 0..143
    const int bh = xx + 8 * (k >= 72);
    k = (k >= 72) ? k - 72 : k;          // 0..71
    int rblk = 0;
    while (k >= 2 * (rblk + 1)) { k -= 2 * (rblk + 1); rblk++; }
    const int sp = k;
    const int b = bh >> 3, h = bh & 7;
    const int j0 = sp * 64;
    const int rbase = rblk * 128;

    const int t = threadIdx.x;
    const int p = t >> 1, dhalf = t & 1;
    const int r0 = rbase + p, r1 = r0 + 64;

    __shared__ float Kl[64 * 64];
    __shared__ float Vl[64 * 64];

    {
        const float* Kbase = K + (size_t)b * S_ * D_ + h * DH_;
        const float* Vbase = V + (size_t)b * S_ * D_ + h * DH_;
        const int lrow = t >> 4, lcol = (t & 15) * 4;
        #pragma unroll
        for (int kk = 0; kk < 8; kk++) {
            const int row = lrow + kk * 8;
            const size_t goff = (size_t)(j0 + row) * D_ + lcol;
            *(float4*)(&Kl[row * 64 + lcol]) = *(const float4*)(Kbase + goff);
            *(float4*)(&Vl[row * 64 + lcol]) = *(const float4*)(Vbase + goff);
        }
    }

    float q0[32], q1[32];
    {
        const float* Qb = Q + (size_t)b * S_ * D_ + h * DH_ + dhalf * 32;
        const float4* qa = (const float4*)(Qb + (size_t)r0 * D_);
        const float4* qb = (const float4*)(Qb + (size_t)r1 * D_);
        #pragma unroll
        for (int kk = 0; kk < 8; kk++) {
            float4 v = qa[kk];
            q0[4*kk] = v.x; q0[4*kk+1] = v.y; q0[4*kk+2] = v.z; q0[4*kk+3] = v.w;
            float4 u = qb[kk];
            q1[4*kk] = u.x; q1[4*kk+1] = u.y; q1[4*kk+2] = u.z; q1[4*kk+3] = u.w;
        }
    }
    float o0[32], o1[32];
    #pragma unroll
    for (int d = 0; d < 32; d++) { o0[d] = 0.f; o1[d] = 0.f; }
    float m0 = -INFINITY, m1 = -INFINITY, l0 = 0.f, l1 = 0.f;

    __syncthreads();

    for (int bb = 0; bb < 8; bb++) {
        const int jb = bb * 8;
        float s0[8], s1[8];
        #pragma unroll
        for (int jj = 0; jj < 8; jj++) {
            const float* kr = &Kl[(jb + jj) * 64 + dhalf * 32];
            float pa0 = 0.f, pb0 = 0.f, pa1 = 0.f, pb1 = 0.f;
            #pragma unroll
            for (int d = 0; d < 32; d += 8) {
                float4 ka = *(const float4*)(kr + d);
                float4 kb = *(const float4*)(kr + d + 4);
                pa0 += q0[d]*ka.x + q0[d+1]*ka.y + q0[d+2]*ka.z + q0[d+3]*ka.w;
                pb0 += q0[d+4]*kb.x + q0[d+5]*kb.y + q0[d+6]*kb.z + q0[d+7]*kb.w;
                pa1 += q1[d]*ka.x + q1[d+1]*ka.y + q1[d+2]*ka.z + q1[d+3]*ka.w;
                pb1 += q1[d+4]*kb.x + q1[d+5]*kb.y + q1[d+6]*kb.z + q1[d+7]*kb.w;
            }
            float f0 = pa0 + pb0, f1 = pa1 + pb1;
            f0 += __shfl_xor(f0, 1);
            f1 += __shfl_xor(f1, 1);
            const int jg = j0 + jb + jj;
            s0[jj] = (jg <= r0) ? f0 * 0.125f : -INFINITY;
            s1[jj] = (jg <= r1) ? f1 * 0.125f : -INFINITY;
        }
        float t0 = s0[0], t1 = s1[0];
        #pragma unroll
        for (int jj = 1; jj < 8; jj++) { t0 = fmaxf(t0, s0[jj]); t1 = fmaxf(t1, s1[jj]); }
        const float nm0 = fmaxf(m0, t0), nm1 = fmaxf(m1, t1);
        const float base0 = (nm0 == -INFINITY) ? 0.f : nm0;
        const float base1 = (nm1 == -INFINITY) ? 0.f : nm1;
        const float al0 = __expf(m0 - base0);
        const float al1 = __expf(m1 - base1);
        float ps0 = 0.f, ps1 = 0.f;
        #pragma unroll
        for (int jj = 0; jj < 8; jj++) {
            s0[jj] = __expf(s0[jj] - base0); ps0 += s0[jj];
            s1[jj] = __expf(s1[jj] - base1); ps1 += s1[jj];
        }
        l0 = l0 * al0 + ps0; l1 = l1 * al1 + ps1;
        #pragma unroll
        for (int d = 0; d < 32; d++) { o0[d] *= al0; o1[d] *= al1; }
        #pragma unroll
        for (int jj = 0; jj < 8; jj++) {
            const float* vr = &Vl[(jb + jj) * 64 + dhalf * 32];
            const float w0 = s0[jj], w1 = s1[jj];
            #pragma unroll
            for (int d = 0; d < 32; d += 4) {
                float4 vv = *(const float4*)(vr + d);
                o0[d]   += w0 * vv.x; o0[d+1] += w0 * vv.y;
                o0[d+2] += w0 * vv.z; o0[d+3] += w0 * vv.w;
                o1[d]   += w1 * vv.x; o1[d+1] += w1 * vv.y;
                o1[d+2] += w1 * vv.z; o1[d+3] += w1 * vv.w;
            }
        }
        m0 = nm0; m1 = nm1;
    }

    if (j0 <= r0) {
        const int g = r0 >> 6;
        const size_t slot = (size_t)bh * NSLOT_BH + 32 * g * (g + 1)
                          + (size_t)(r0 & 63) * (g + 1) + sp;
        if (dhalf == 0) { pm[slot] = m0; pl[slot] = l0; }
        float* od = po + slot * 64 + dhalf * 32;
        #pragma unroll
        for (int kk = 0; kk < 8; kk++) {
            float4 v; v.x = o0[4*kk]; v.y = o0[4*kk+1]; v.z = o0[4*kk+2]; v.w = o0[4*kk+3];
            *(float4*)(od + 4*kk) = v;
        }
    }
    {
        const int g = r1 >> 6;
        const size_t slot = (size_t)bh * NSLOT_BH + 32 * g * (g + 1)
                          + (size_t)(r1 & 63) * (g + 1) + sp;
        if (dhalf == 0) { pm[slot] = m1; pl[slot] = l1; }
        float* od = po + slot * 64 + dhalf * 32;
        #pragma unroll
        for (int kk = 0; kk < 8; kk++) {
            float4 v; v.x = o1[4*kk]; v.y = o1[4*kk+1]; v.z = o1[4*kk+2]; v.w = o1[4*kk+3];
            *(float4*)(od + 4*kk) = v;
        }
    }
}

// ---------- merge split partials (compact layout) ----------
__global__ __launch_bounds__(256) void attn_combine_kernel(
    const float* __restrict__ pm, const float* __restrict__ pl,
    const float* __restrict__ po, float* __restrict__ AO)
{
    const int gth = blockIdx.x * 256 + threadIdx.x;
    const int r = gth >> 6, d = gth & 63;
    const int i = r & 1023, bh = r >> 10;
    const int b = bh >> 3, h = bh & 7;
    const int g = i >> 6;
    const int ns = g + 1;
    const size_t slot0 = (size_t)bh * NSLOT_BH + 32 * g * (g + 1)
                       + (size_t)(i & 63) * (g + 1);
    float mstar = -INFINITY;
    for (int s = 0; s < ns; s++) mstar = fmaxf(mstar, pm[slot0 + s]);
    float lstar = 0.f, ostar = 0.f;
    for (int s = 0; s < ns; s++) {
        const float w = __expf(pm[slot0 + s] - mstar);
        lstar += pl[slot0 + s] * w;
        ostar += po[(slot0 + s) * 64 + d] * w;
    }
    AO[((size_t)(b * S_ + i)) * D_ + h * DH_ + d] = ostar / lstar;
}

// ---------- projection: 4 tokens per block ----------
__global__ __launch_bounds__(256) void proj_kernel(
    const float* __restrict__ A, const float* __restrict__ W,
    float* __restrict__ out)
{
    __shared__ float rows[4][D_];
    const int blk = blockIdx.x;
    const int t = threadIdx.x;
    {
        const float4* af = (const float4*)(A + (size_t)blk * 4 * D_);
        float4* rf = (float4*)&rows[0][0];
        rf[t] = af[t]; rf[t + 256] = af[t + 256];
    }
    __syncthreads();
    float acc0[4] = {0,0,0,0}, acc1[4] = {0,0,0,0};
    for (int d = 0; d < D_; d += 4) {
        float r0[4], r1[4], r2[4], r3[4];
        *(float4*)r0 = *(const float4*)&rows[0][d];
        *(float4*)r1 = *(const float4*)&rows[1][d];
        *(float4*)r2 = *(const float4*)&rows[2][d];
        *(float4*)r3 = *(const float4*)&rows[3][d];
        #pragma unroll
        for (int j = 0; j < 4; j++) {
            float w0 = W[(size_t)(d + j) * D_ + t];
            float w1 = W[(size_t)(d + j) * D_ + t + 256];
            acc0[0] += r0[j] * w0; acc1[0] += r0[j] * w1;
            acc0[1] += r1[j] * w0; acc1[1] += r1[j] * w1;
            acc0[2] += r2[j] * w0; acc1[2] += r2[j] * w1;
            acc0[3] += r3[j] * w0; acc1[3] += r3[j] * w1;
        }
    }
    #pragma unroll
    for (int k = 0; k < 4; k++) {
        const size_t base = (size_t)(blk * 4 + k) * D_;
        out[base + t] = acc0[k];
        out[base + t + 256] = acc1[k];
    }
}

// ---------- pos-loss helpers ----------
__global__ void zero_acc_kernel(float* acc) {
    if (threadIdx.x < 32) acc[threadIdx.x] = 0.f;
}
__global__ void ploss_kernel(const float* __restrict__ acc, float* __restrict__ out) {
    float ssum = 0.f;
    for (int c = 0; c < 8; c++) {
        ssum += acc[c]      / (acc[8 + c]  + 1e-8f);
        ssum += acc[16 + c] / (acc[24 + c] + 1e-8f);
    }
    out[0] = ssum * 0.125f;
}

extern "C" void kernel_launch(void* const* d_in, const int* in_sizes, int n_in,
                              void* d_out, int out_size, void* d_ws, size_t ws_size,
                              hipStream_t stream) {
    const float* x          = (const float*)d_in[0];
    const float* qk_pos     = (const float*)d_in[1];
    const float* v_pos      = (const float*)d_in[2];
    const float* tauQ       = (const float*)d_in[3];
    const float* tauK       = (const float*)d_in[4];
    const float* tauV       = (const float*)d_in[5];
    const float* qk_neurons = (const float*)d_in[6];
    const float* v_neurons  = (const float*)d_in[7];
    const float* npos_qk    = (const float*)d_in[8];
    const float* npos_v     = (const float*)d_in[9];
    const int*   cm_qk      = (const int*)d_in[10];
    const int*   cm_v       = (const int*)d_in[11];
    const float* pos_min    = (const float*)d_in[12];
    const float* pos_range  = (const float*)d_in[13];
    const float* expand_O   = (const float*)d_in[14];

    float* ws = (float*)d_ws;
    const size_t TDf = (size_t)NTOK * D_;     // 1,048,576 floats
    float* Q   = ws;
    float* K   = ws + TDf;
    float* V   = ws + 2 * TDf;
    float* AO  = ws + 3 * TDf;
    float* acc = ws + 4 * TDf;                // 64 float slots
    int*   order_qk = (int*)(ws + 4 * TDf + 64);
    int*   order_v  = order_qk + NTOK;
    int2*  desc_qk  = (int2*)(order_v + NTOK);
    int2*  desc_v   = desc_qk + NGROUPS;
    const size_t head = 4 * TDf + 64 + 2 * NTOK + 4 * NGROUPS;  // float units

    float* pm = ws + head;                    // NSLOTS
    float* pl = pm + (size_t)NSLOTS;
    float* po = pl + (size_t)NSLOTS;          // NSLOTS*64

    float* out = (float*)d_out;

    zero_acc_kernel<<<1, 64, 0, stream>>>(acc);
    sort_tokens_kernel<<<1, 1024, 0, stream>>>(qk_pos, v_pos, pos_min, pos_range,
                                               order_qk, order_v, desc_qk, desc_v);
    qk_kernel<<<NGROUPS, 256, 0, stream>>>(desc_qk, order_qk, x, qk_pos, tauQ, tauK,
                                           qk_neurons, npos_qk, cm_qk,
                                           pos_min, pos_range, Q, K, acc);
    v_kernel<<<NGROUPS, 256, 0, stream>>>(desc_v, order_v, x, v_pos, tauV,
                                          v_neurons, npos_v, cm_v,
                                          pos_min, pos_range, V, acc);
    attn_partial_kernel<<<1152, 128, 0, stream>>>(Q, K, V, pm, pl, po);
    attn_combine_kernel<<<(NROWS * 64) / 256, 256, 0, stream>>>(pm, pl, po, AO);
    proj_kernel<<<NTOK / 4, 256, 0, stream>>>(AO, expand_O, out);
    ploss_kernel<<<1, 1, 0, stream>>>(acc, out + TDf);
}

// Round 7
// 455.217 us; speedup vs baseline: 1.2241x; 1.2241x over previous
//
#include <hip/hip_runtime.h>
#include <math.h>

#define B_ 2
#define S_ 1024
#define D_ 512
#define N_ 4096
#define H_ 8
#define DH_ 64
#define NCAND 288   // 9 neighbor cells * 32 entries
#define TOPK 32
#define NTOK (B_*S_)   // 2048

#define NROWS 16384       // B*H*S
#define NSLOT_BH 8704     // sum over rows i<1024 of (i/64+1)
#define NSLOTS (16*NSLOT_BH)

// ---------- block-wide reductions (256 threads = 4 waves) ----------
__device__ __forceinline__ float blk_sum(float v, float* sc) {
    #pragma unroll
    for (int o = 32; o; o >>= 1) v += __shfl_xor(v, o);
    __syncthreads();
    if ((threadIdx.x & 63) == 0) sc[threadIdx.x >> 6] = v;
    __syncthreads();
    return sc[0] + sc[1] + sc[2] + sc[3];
}
__device__ __forceinline__ float blk_max(float v, float* sc) {
    #pragma unroll
    for (int o = 32; o; o >>= 1) v = fmaxf(v, __shfl_xor(v, o));
    __syncthreads();
    if ((threadIdx.x & 63) == 0) sc[threadIdx.x >> 6] = v;
    __syncthreads();
    return fmaxf(fmaxf(sc[0], sc[1]), fmaxf(sc[2], sc[3]));
}

__device__ __forceinline__ float dot8(const float4& xa, const float4& xb,
                                      const float4& ra, const float4& rb) {
    return xa.x * ra.x + xa.y * ra.y + xa.z * ra.z + xa.w * ra.w +
           xb.x * rb.x + xb.y * rb.y + xb.z * rb.z + xb.w * rb.w;
}

// ---------- token sort by spatial cell (1 block, 1024 threads) ----------
__global__ __launch_bounds__(1024) void sort_tokens_kernel(
    const float* __restrict__ qk_pos, const float* __restrict__ v_pos,
    const float* __restrict__ pos_min, const float* __restrict__ pos_range,
    int* __restrict__ order_qk, int* __restrict__ order_v)
{
    __shared__ int hist[256], offs[256], tmp[256];
    const int t = threadIdx.x;
    const float pm0 = pos_min[0], pm1 = pos_min[1];
    const float pr0 = pos_range[0], pr1 = pos_range[1];
    for (int pass = 0; pass < 2; pass++) {
        const float* pos = pass ? v_pos : qk_pos;
        int* order = pass ? order_v : order_qk;
        if (t < 256) hist[t] = 0;
        __syncthreads();
        int cell[2];
        #pragma unroll
        for (int k = 0; k < 2; k++) {
            int tok = t + k * 1024;
            float p0 = pos[tok * 2], p1 = pos[tok * 2 + 1];
            int cx = min(max((int)((p0 - pm0) / pr0 * 16.f), 0), 15);
            int cy = min(max((int)((p1 - pm1) / pr1 * 16.f), 0), 15);
            cell[k] = cx * 16 + cy;
            atomicAdd(&hist[cell[k]], 1);
        }
        __syncthreads();
        if (t < 256) tmp[t] = hist[t];
        __syncthreads();
        for (int d = 1; d < 256; d <<= 1) {
            int v = 0;
            if (t < 256 && t >= d) v = tmp[t - d];
            __syncthreads();
            if (t < 256) tmp[t] += v;
            __syncthreads();
        }
        if (t < 256) offs[t] = tmp[t] - hist[t];
        __syncthreads();
        #pragma unroll
        for (int k = 0; k < 2; k++) {
            int tok = t + k * 1024;
            int p = atomicAdd(&offs[cell[k]], 1);
            order[p] = tok;
        }
        __syncthreads();
    }
}

// ---------- QK kernel: one block per token (sorted order, XCD-swizzled) ----------
// Dot loop: 4 candidates in flight (8 float4 loads issued together, 4
// independent FMA+butterfly chains) — hides L2 + shfl latency.
__global__ __launch_bounds__(256) void qk_kernel(
    const int* __restrict__ order,
    const float* __restrict__ x, const float* __restrict__ qk_pos,
    const float* __restrict__ tauQ, const float* __restrict__ tauK,
    const float* __restrict__ neurons, const float* __restrict__ npos,
    const int* __restrict__ cmap,
    const float* __restrict__ pos_min, const float* __restrict__ pos_range,
    float* __restrict__ Q, float* __restrict__ K, float* __restrict__ posacc)
{
    __shared__ int   idx[NCAND];
    __shared__ float msk[NCAND], act[NCAND];
    __shared__ int   ci[NCAND];
    __shared__ float cwq[NCAND], cwk[NCAND];
    __shared__ float sc[4];
    __shared__ int   cnt;

    const int pos = (blockIdx.x >> 3) | ((blockIdx.x & 7) << 8);  // XCD swizzle
    const int token = order[pos];
    const int s_pos = token & 1023;
    const int t = threadIdx.x, wid = t >> 6, lane = t & 63;

    const float qp0 = qk_pos[token * 2], qp1 = qk_pos[token * 2 + 1];
    const float pm0 = pos_min[0], pm1 = pos_min[1];
    const float pr0 = pos_range[0], pr1 = pos_range[1];
    const int cx = min(max((int)((qp0 - pm0) / pr0 * 16.f), 0), 15);
    const int cy = min(max((int)((qp1 - pm1) / pr1 * 16.f), 0), 15);
    for (int c = t; c < NCAND; c += 256) {
        int o = c >> 5, mslot = c & 31;
        int nx = min(max(cx + o / 3 - 1, 0), 15), ny = min(max(cy + o % 3 - 1, 0), 15);
        int cand = cmap[(nx * 16 + ny) * 32 + mslot];
        idx[c] = cand >= 0 ? cand : 0;
        msk[c] = cand >= 0 ? 1.f : 0.f;
    }
    if (t == 0) cnt = 0;
    __syncthreads();

    // --- dots: wave-per-candidate, 4-wide ILP ---
    const float4* x4 = (const float4*)(x + (size_t)token * D_);
    const float4 xa = x4[lane * 2], xb = x4[lane * 2 + 1];
    const int cbase = wid * 72;
    for (int u = 0; u < 72; u += 4) {
        const int c = cbase + u;
        const float4* r0 = (const float4*)(neurons + (size_t)idx[c + 0] * D_);
        const float4* r1 = (const float4*)(neurons + (size_t)idx[c + 1] * D_);
        const float4* r2 = (const float4*)(neurons + (size_t)idx[c + 2] * D_);
        const float4* r3 = (const float4*)(neurons + (size_t)idx[c + 3] * D_);
        float4 ra0 = r0[lane * 2], rb0 = r0[lane * 2 + 1];
        float4 ra1 = r1[lane * 2], rb1 = r1[lane * 2 + 1];
        float4 ra2 = r2[lane * 2], rb2 = r2[lane * 2 + 1];
        float4 ra3 = r3[lane * 2], rb3 = r3[lane * 2 + 1];
        float a0 = dot8(xa, xb, ra0, rb0);
        float a1 = dot8(xa, xb, ra1, rb1);
        float a2 = dot8(xa, xb, ra2, rb2);
        float a3 = dot8(xa, xb, ra3, rb3);
        #pragma unroll
        for (int o = 32; o; o >>= 1) {
            a0 += __shfl_xor(a0, o);
            a1 += __shfl_xor(a1, o);
            a2 += __shfl_xor(a2, o);
            a3 += __shfl_xor(a3, o);
        }
        if (lane == 0) {
            act[c + 0] = (msk[c + 0] != 0.f) ? a0 : -1e9f;
            act[c + 1] = (msk[c + 1] != 0.f) ? a1 : -1e9f;
            act[c + 2] = (msk[c + 2] != 0.f) ? a2 : -1e9f;
            act[c + 3] = (msk[c + 3] != 0.f) ? a3 : -1e9f;
        }
    }
    __syncthreads();

    // --- rank by act via ballot+popcount; compact kept slots ---
    float ej[5];
    #pragma unroll
    for (int k = 0; k < 5; k++) {
        int j = lane + 64 * k;
        ej[k] = (j < NCAND) ? act[j] : -1e30f;
    }
    for (int e = wid * 72; e < wid * 72 + 72; e++) {
        float ev = act[e];
        int cgt = 0;
        #pragma unroll
        for (int k = 0; k < 5; k++)
            cgt += __popcll(__ballot(ej[k] > ev));
        if (lane == 0 && cgt < TOPK) {
            int p = atomicAdd(&cnt, 1);
            ci[p] = e;
        }
    }
    __syncthreads();
    const int n = cnt;

    // --- gates on kept only ---
    const float tq = tauQ[token], tk = tauK[token];
    float sQ = 0.f, sK = 0.f, mQ = 0.f, mK = 0.f;
    for (int p = t; p < n; p += 256) {
        float s = act[ci[p]];
        float rq = s - tq;
        float gq = (rq > 0.f) ? rq : 1e-8f * __expf(rq);
        float egq = __expf(gq) - 1.f;
        float rk = s - tk;
        float gk = (rk > 0.f) ? rk : 1e-8f * __expf(rk);
        float egk = __expf(gk) - 1.f;
        cwq[p] = egq; cwk[p] = egk;
        sQ += egq; sK += egk;
        mQ = fmaxf(mQ, egq); mK = fmaxf(mK, egk);
    }
    sQ = blk_sum(sQ, sc); mQ = blk_max(mQ, sc);
    sK = blk_sum(sK, sc); mK = blk_max(mK, sc);
    const float scQ = tanhf(mQ) / (sQ + 1e-8f);
    const float scK = tanhf(mK) / (sK + 1e-8f);

    float cm = 0.f;
    for (int c = t; c < NCAND; c += 256) cm += msk[c];
    cm = blk_sum(cm, sc);

    float plq = 0.f;
    for (int p = t; p < n; p += 256) {
        int e = ci[p];
        int id = idx[e];
        float m = msk[e], a = act[e];
        float gq = cwq[p] * scQ;
        cwq[p] = a * gq * m;
        cwk[p] = a * cwk[p] * scK * m;
        ci[p] = id;
        float d0 = qp0 - npos[id * 2], d1 = qp1 - npos[id * 2 + 1];
        plq += gq * (d0 * d0 + d1 * d1) * m;
    }
    plq = blk_sum(plq, sc);
    if (t == 0) {
        int chunk = s_pos >> 7;
        atomicAdd(&posacc[chunk], plq);
        atomicAdd(&posacc[8 + chunk], cm);
    }
    __syncthreads();

    // --- accumulate Q,K over kept rows, 2 rows in flight ---
    float q0 = 0, q1 = 0, k0 = 0, k1 = 0;
    int p = 0;
    for (; p + 1 < n; p += 2) {
        const float* rowA = neurons + (size_t)ci[p] * D_;
        const float* rowB = neurons + (size_t)ci[p + 1] * D_;
        float rA0 = rowA[t], rA1 = rowA[t + 256];
        float rB0 = rowB[t], rB1 = rowB[t + 256];
        float awA = cwq[p], bwA = cwk[p];
        float awB = cwq[p + 1], bwB = cwk[p + 1];
        q0 += awA * rA0 + awB * rB0;  q1 += awA * rA1 + awB * rB1;
        k0 += bwA * rA0 + bwB * rB0;  k1 += bwA * rA1 + bwB * rB1;
    }
    if (p < n) {
        const float* row = neurons + (size_t)ci[p] * D_;
        float r0 = row[t], r1 = row[t + 256];
        q0 += cwq[p] * r0; q1 += cwq[p] * r1;
        k0 += cwk[p] * r0; k1 += cwk[p] * r1;
    }
    const size_t base = (size_t)token * D_;
    Q[base + t] = q0; Q[base + t + 256] = q1;
    K[base + t] = k0; K[base + t + 256] = k1;
}

// ---------- V kernel (same structure, single gate) ----------
__global__ __launch_bounds__(256) void v_kernel(
    const int* __restrict__ order,
    const float* __restrict__ x, const float* __restrict__ v_pos,
    const float* __restrict__ tauV,
    const float* __restrict__ neurons, const float* __restrict__ npos,
    const int* __restrict__ cmap,
    const float* __restrict__ pos_min, const float* __restrict__ pos_range,
    float* __restrict__ V, float* __restrict__ posacc)
{
    __shared__ int   idx[NCAND];
    __shared__ float msk[NCAND], act[NCAND];
    __shared__ int   ci[NCAND];
    __shared__ float cwv[NCAND];
    __shared__ float sc[4];
    __shared__ int   cnt;

    const int pos = (blockIdx.x >> 3) | ((blockIdx.x & 7) << 8);
    const int token = order[pos];
    const int s_pos = token & 1023;
    const int t = threadIdx.x, wid = t >> 6, lane = t & 63;

    const float vp0 = v_pos[token * 2], vp1 = v_pos[token * 2 + 1];
    const float pm0 = pos_min[0], pm1 = pos_min[1];
    const float pr0 = pos_range[0], pr1 = pos_range[1];
    const int cx = min(max((int)((vp0 - pm0) / pr0 * 16.f), 0), 15);
    const int cy = min(max((int)((vp1 - pm1) / pr1 * 16.f), 0), 15);
    for (int c = t; c < NCAND; c += 256) {
        int o = c >> 5, mslot = c & 31;
        int nx = min(max(cx + o / 3 - 1, 0), 15), ny = min(max(cy + o % 3 - 1, 0), 15);
        int cand = cmap[(nx * 16 + ny) * 32 + mslot];
        idx[c] = cand >= 0 ? cand : 0;
        msk[c] = cand >= 0 ? 1.f : 0.f;
    }
    if (t == 0) cnt = 0;
    __syncthreads();

    const float4* x4 = (const float4*)(x + (size_t)token * D_);
    const float4 xa = x4[lane * 2], xb = x4[lane * 2 + 1];
    const int cbase = wid * 72;
    for (int u = 0; u < 72; u += 4) {
        const int c = cbase + u;
        const float4* r0 = (const float4*)(neurons + (size_t)idx[c + 0] * D_);
        const float4* r1 = (const float4*)(neurons + (size_t)idx[c + 1] * D_);
        const float4* r2 = (const float4*)(neurons + (size_t)idx[c + 2] * D_);
        const float4* r3 = (const float4*)(neurons + (size_t)idx[c + 3] * D_);
        float4 ra0 = r0[lane * 2], rb0 = r0[lane * 2 + 1];
        float4 ra1 = r1[lane * 2], rb1 = r1[lane * 2 + 1];
        float4 ra2 = r2[lane * 2], rb2 = r2[lane * 2 + 1];
        float4 ra3 = r3[lane * 2], rb3 = r3[lane * 2 + 1];
        float a0 = dot8(xa, xb, ra0, rb0);
        float a1 = dot8(xa, xb, ra1, rb1);
        float a2 = dot8(xa, xb, ra2, rb2);
        float a3 = dot8(xa, xb, ra3, rb3);
        #pragma unroll
        for (int o = 32; o; o >>= 1) {
            a0 += __shfl_xor(a0, o);
            a1 += __shfl_xor(a1, o);
            a2 += __shfl_xor(a2, o);
            a3 += __shfl_xor(a3, o);
        }
        if (lane == 0) {
            act[c + 0] = (msk[c + 0] != 0.f) ? a0 : -1e9f;
            act[c + 1] = (msk[c + 1] != 0.f) ? a1 : -1e9f;
            act[c + 2] = (msk[c + 2] != 0.f) ? a2 : -1e9f;
            act[c + 3] = (msk[c + 3] != 0.f) ? a3 : -1e9f;
        }
    }
    __syncthreads();

    float ej[5];
    #pragma unroll
    for (int k = 0; k < 5; k++) {
        int j = lane + 64 * k;
        ej[k] = (j < NCAND) ? act[j] : -1e30f;
    }
    for (int e = wid * 72; e < wid * 72 + 72; e++) {
        float ev = act[e];
        int cgt = 0;
        #pragma unroll
        for (int k = 0; k < 5; k++)
            cgt += __popcll(__ballot(ej[k] > ev));
        if (lane == 0 && cgt < TOPK) {
            int p = atomicAdd(&cnt, 1);
            ci[p] = e;
        }
    }
    __syncthreads();
    const int n = cnt;

    const float tv = tauV[token];
    float sV = 0.f, mV = 0.f;
    for (int p = t; p < n; p += 256) {
        float s = act[ci[p]];
        float rv = s - tv;
        float gv = (rv > 0.f) ? rv : 1e-8f * __expf(rv);
        float egv = __expf(gv) - 1.f;
        cwv[p] = egv;
        sV += egv; mV = fmaxf(mV, egv);
    }
    sV = blk_sum(sV, sc); mV = blk_max(mV, sc);
    const float scV = tanhf(mV) / (sV + 1e-8f);

    float cm = 0.f;
    for (int c = t; c < NCAND; c += 256) cm += msk[c];
    cm = blk_sum(cm, sc);

    float plv = 0.f;
    for (int p = t; p < n; p += 256) {
        int e = ci[p];
        int id = idx[e];
        float m = msk[e], a = act[e];
        float gv = cwv[p] * scV;
        cwv[p] = a * gv * m;
        ci[p] = id;
        float d0 = vp0 - npos[id * 2], d1 = vp1 - npos[id * 2 + 1];
        plv += gv * (d0 * d0 + d1 * d1) * m;
    }
    plv = blk_sum(plv, sc);
    if (t == 0) {
        int chunk = s_pos >> 7;
        atomicAdd(&posacc[16 + chunk], plv);
        atomicAdd(&posacc[24 + chunk], cm);
    }
    __syncthreads();

    float v0 = 0, v1 = 0;
    int p = 0;
    for (; p + 1 < n; p += 2) {
        const float* rowA = neurons + (size_t)ci[p] * D_;
        const float* rowB = neurons + (size_t)ci[p + 1] * D_;
        float rA0 = rowA[t], rA1 = rowA[t + 256];
        float rB0 = rowB[t], rB1 = rowB[t + 256];
        v0 += cwv[p] * rA0 + cwv[p + 1] * rB0;
        v1 += cwv[p] * rA1 + cwv[p + 1] * rB1;
    }
    if (p < n) {
        const float* row = neurons + (size_t)ci[p] * D_;
        v0 += cwv[p] * row[t]; v1 += cwv[p] * row[t + 256];
    }
    const size_t base = (size_t)token * D_;
    V[base + t] = v0; V[base + t + 256] = v1;
}

// ---------- attention partials (unchanged from R5) ----------
__global__ __launch_bounds__(128) void attn_partial_kernel(
    const float* __restrict__ Q, const float* __restrict__ K,
    const float* __restrict__ V,
    float* __restrict__ pm, float* __restrict__ pl, float* __restrict__ po)
{
    const int xx = blockIdx.x & 7;
    int k = blockIdx.x >> 3;             // 0..143
    const int bh = xx + 8 * (k >= 72);
    k = (k >= 72) ? k - 72 : k;          // 0..71
    int rblk = 0;
    while (k >= 2 * (rblk + 1)) { k -= 2 * (rblk + 1); rblk++; }
    const int sp = k;
    const int b = bh >> 3, h = bh & 7;
    const int j0 = sp * 64;
    const int rbase = rblk * 128;

    const int t = threadIdx.x;
    const int p = t >> 1, dhalf = t & 1;
    const int r0 = rbase + p, r1 = r0 + 64;

    __shared__ float Kl[64 * 64];
    __shared__ float Vl[64 * 64];

    {
        const float* Kbase = K + (size_t)b * S_ * D_ + h * DH_;
        const float* Vbase = V + (size_t)b * S_ * D_ + h * DH_;
        const int lrow = t >> 4, lcol = (t & 15) * 4;
        #pragma unroll
        for (int kk = 0; kk < 8; kk++) {
            const int row = lrow + kk * 8;
            const size_t goff = (size_t)(j0 + row) * D_ + lcol;
            *(float4*)(&Kl[row * 64 + lcol]) = *(const float4*)(Kbase + goff);
            *(float4*)(&Vl[row * 64 + lcol]) = *(const float4*)(Vbase + goff);
        }
    }

    float q0[32], q1[32];
    {
        const float* Qb = Q + (size_t)b * S_ * D_ + h * DH_ + dhalf * 32;
        const float4* qa = (const float4*)(Qb + (size_t)r0 * D_);
        const float4* qb = (const float4*)(Qb + (size_t)r1 * D_);
        #pragma unroll
        for (int kk = 0; kk < 8; kk++) {
            float4 v = qa[kk];
            q0[4*kk] = v.x; q0[4*kk+1] = v.y; q0[4*kk+2] = v.z; q0[4*kk+3] = v.w;
            float4 u = qb[kk];
            q1[4*kk] = u.x; q1[4*kk+1] = u.y; q1[4*kk+2] = u.z; q1[4*kk+3] = u.w;
        }
    }
    float o0[32], o1[32];
    #pragma unroll
    for (int d = 0; d < 32; d++) { o0[d] = 0.f; o1[d] = 0.f; }
    float m0 = -INFINITY, m1 = -INFINITY, l0 = 0.f, l1 = 0.f;

    __syncthreads();

    for (int bb = 0; bb < 8; bb++) {
        const int jb = bb * 8;
        float s0[8], s1[8];
        #pragma unroll
        for (int jj = 0; jj < 8; jj++) {
            const float* kr = &Kl[(jb + jj) * 64 + dhalf * 32];
            float pa0 = 0.f, pb0 = 0.f, pa1 = 0.f, pb1 = 0.f;
            #pragma unroll
            for (int d = 0; d < 32; d += 8) {
                float4 ka = *(const float4*)(kr + d);
                float4 kb = *(const float4*)(kr + d + 4);
                pa0 += q0[d]*ka.x + q0[d+1]*ka.y + q0[d+2]*ka.z + q0[d+3]*ka.w;
                pb0 += q0[d+4]*kb.x + q0[d+5]*kb.y + q0[d+6]*kb.z + q0[d+7]*kb.w;
                pa1 += q1[d]*ka.x + q1[d+1]*ka.y + q1[d+2]*ka.z + q1[d+3]*ka.w;
                pb1 += q1[d+4]*kb.x + q1[d+5]*kb.y + q1[d+6]*kb.z + q1[d+7]*kb.w;
            }
            float f0 = pa0 + pb0, f1 = pa1 + pb1;
            f0 += __shfl_xor(f0, 1);
            f1 += __shfl_xor(f1, 1);
            const int jg = j0 + jb + jj;
            s0[jj] = (jg <= r0) ? f0 * 0.125f : -INFINITY;
            s1[jj] = (jg <= r1) ? f1 * 0.125f : -INFINITY;
        }
        float t0 = s0[0], t1 = s1[0];
        #pragma unroll
        for (int jj = 1; jj < 8; jj++) { t0 = fmaxf(t0, s0[jj]); t1 = fmaxf(t1, s1[jj]); }
        const float nm0 = fmaxf(m0, t0), nm1 = fmaxf(m1, t1);
        const float base0 = (nm0 == -INFINITY) ? 0.f : nm0;
        const float base1 = (nm1 == -INFINITY) ? 0.f : nm1;
        const float al0 = __expf(m0 - base0);
        const float al1 = __expf(m1 - base1);
        float ps0 = 0.f, ps1 = 0.f;
        #pragma unroll
        for (int jj = 0; jj < 8; jj++) {
            s0[jj] = __expf(s0[jj] - base0); ps0 += s0[jj];
            s1[jj] = __expf(s1[jj] - base1); ps1 += s1[jj];
        }
        l0 = l0 * al0 + ps0; l1 = l1 * al1 + ps1;
        #pragma unroll
        for (int d = 0; d < 32; d++) { o0[d] *= al0; o1[d] *= al1; }
        #pragma unroll
        for (int jj = 0; jj < 8; jj++) {
            const float* vr = &Vl[(jb + jj) * 64 + dhalf * 32];
            const float w0 = s0[jj], w1 = s1[jj];
            #pragma unroll
            for (int d = 0; d < 32; d += 4) {
                float4 vv = *(const float4*)(vr + d);
                o0[d]   += w0 * vv.x; o0[d+1] += w0 * vv.y;
                o0[d+2] += w0 * vv.z; o0[d+3] += w0 * vv.w;
                o1[d]   += w1 * vv.x; o1[d+1] += w1 * vv.y;
                o1[d+2] += w1 * vv.z; o1[d+3] += w1 * vv.w;
            }
        }
        m0 = nm0; m1 = nm1;
    }

    if (j0 <= r0) {
        const int g = r0 >> 6;
        const size_t slot = (size_t)bh * NSLOT_BH + 32 * g * (g + 1)
                          + (size_t)(r0 & 63) * (g + 1) + sp;
        if (dhalf == 0) { pm[slot] = m0; pl[slot] = l0; }
        float* od = po + slot * 64 + dhalf * 32;
        #pragma unroll
        for (int kk = 0; kk < 8; kk++) {
            float4 v; v.x = o0[4*kk]; v.y = o0[4*kk+1]; v.z = o0[4*kk+2]; v.w = o0[4*kk+3];
            *(float4*)(od + 4*kk) = v;
        }
    }
    {
        const int g = r1 >> 6;
        const size_t slot = (size_t)bh * NSLOT_BH + 32 * g * (g + 1)
                          + (size_t)(r1 & 63) * (g + 1) + sp;
        if (dhalf == 0) { pm[slot] = m1; pl[slot] = l1; }
        float* od = po + slot * 64 + dhalf * 32;
        #pragma unroll
        for (int kk = 0; kk < 8; kk++) {
            float4 v; v.x = o1[4*kk]; v.y = o1[4*kk+1]; v.z = o1[4*kk+2]; v.w = o1[4*kk+3];
            *(float4*)(od + 4*kk) = v;
        }
    }
}

// ---------- merge split partials (compact layout) ----------
__global__ __launch_bounds__(256) void attn_combine_kernel(
    const float* __restrict__ pm, const float* __restrict__ pl,
    const float* __restrict__ po, float* __restrict__ AO)
{
    const int gth = blockIdx.x * 256 + threadIdx.x;
    const int r = gth >> 6, d = gth & 63;
    const int i = r & 1023, bh = r >> 10;
    const int b = bh >> 3, h = bh & 7;
    const int g = i >> 6;
    const int ns = g + 1;
    const size_t slot0 = (size_t)bh * NSLOT_BH + 32 * g * (g + 1)
                       + (size_t)(i & 63) * (g + 1);
    float mstar = -INFINITY;
    for (int s = 0; s < ns; s++) mstar = fmaxf(mstar, pm[slot0 + s]);
    float lstar = 0.f, ostar = 0.f;
    for (int s = 0; s < ns; s++) {
        const float w = __expf(pm[slot0 + s] - mstar);
        lstar += pl[slot0 + s] * w;
        ostar += po[(slot0 + s) * 64 + d] * w;
    }
    AO[((size_t)(b * S_ + i)) * D_ + h * DH_ + d] = ostar / lstar;
}

// ---------- projection: 4 tokens per block ----------
__global__ __launch_bounds__(256) void proj_kernel(
    const float* __restrict__ A, const float* __restrict__ W,
    float* __restrict__ out)
{
    __shared__ float rows[4][D_];
    const int blk = blockIdx.x;
    const int t = threadIdx.x;
    {
        const float4* af = (const float4*)(A + (size_t)blk * 4 * D_);
        float4* rf = (float4*)&rows[0][0];
        rf[t] = af[t]; rf[t + 256] = af[t + 256];
    }
    __syncthreads();
    float acc0[4] = {0,0,0,0}, acc1[4] = {0,0,0,0};
    for (int d = 0; d < D_; d += 4) {
        float r0[4], r1[4], r2[4], r3[4];
        *(float4*)r0 = *(const float4*)&rows[0][d];
        *(float4*)r1 = *(const float4*)&rows[1][d];
        *(float4*)r2 = *(const float4*)&rows[2][d];
        *(float4*)r3 = *(const float4*)&rows[3][d];
        #pragma unroll
        for (int j = 0; j < 4; j++) {
            float w0 = W[(size_t)(d + j) * D_ + t];
            float w1 = W[(size_t)(d + j) * D_ + t + 256];
            acc0[0] += r0[j] * w0; acc1[0] += r0[j] * w1;
            acc0[1] += r1[j] * w0; acc1[1] += r1[j] * w1;
            acc0[2] += r2[j] * w0; acc1[2] += r2[j] * w1;
            acc0[3] += r3[j] * w0; acc1[3] += r3[j] * w1;
        }
    }
    #pragma unroll
    for (int k = 0; k < 4; k++) {
        const size_t base = (size_t)(blk * 4 + k) * D_;
        out[base + t] = acc0[k];
        out[base + t + 256] = acc1[k];
    }
}

// ---------- pos-loss helpers ----------
__global__ void zero_acc_kernel(float* acc) {
    if (threadIdx.x < 32) acc[threadIdx.x] = 0.f;
}
__global__ void ploss_kernel(const float* __restrict__ acc, float* __restrict__ out) {
    float ssum = 0.f;
    for (int c = 0; c < 8; c++) {
        ssum += acc[c]      / (acc[8 + c]  + 1e-8f);
        ssum += acc[16 + c] / (acc[24 + c] + 1e-8f);
    }
    out[0] = ssum * 0.125f;
}

extern "C" void kernel_launch(void* const* d_in, const int* in_sizes, int n_in,
                              void* d_out, int out_size, void* d_ws, size_t ws_size,
                              hipStream_t stream) {
    const float* x          = (const float*)d_in[0];
    const float* qk_pos     = (const float*)d_in[1];
    const float* v_pos      = (const float*)d_in[2];
    const float* tauQ       = (const float*)d_in[3];
    const float* tauK       = (const float*)d_in[4];
    const float* tauV       = (const float*)d_in[5];
    const float* qk_neurons = (const float*)d_in[6];
    const float* v_neurons  = (const float*)d_in[7];
    const float* npos_qk    = (const float*)d_in[8];
    const float* npos_v     = (const float*)d_in[9];
    const int*   cm_qk      = (const int*)d_in[10];
    const int*   cm_v       = (const int*)d_in[11];
    const float* pos_min    = (const float*)d_in[12];
    const float* pos_range  = (const float*)d_in[13];
    const float* expand_O   = (const float*)d_in[14];

    float* ws = (float*)d_ws;
    const size_t TDf = (size_t)NTOK * D_;     // 1,048,576 floats
    float* Q   = ws;
    float* K   = ws + TDf;
    float* V   = ws + 2 * TDf;
    float* AO  = ws + 3 * TDf;
    float* acc = ws + 4 * TDf;                // 64 float slots
    int*   order_qk = (int*)(ws + 4 * TDf + 64);
    int*   order_v  = order_qk + NTOK;
    const size_t head = 4 * TDf + 64 + 2 * NTOK;   // float units

    float* pm = ws + head;                    // NSLOTS
    float* pl = pm + (size_t)NSLOTS;
    float* po = pl + (size_t)NSLOTS;          // NSLOTS*64

    float* out = (float*)d_out;

    zero_acc_kernel<<<1, 64, 0, stream>>>(acc);
    sort_tokens_kernel<<<1, 1024, 0, stream>>>(qk_pos, v_pos, pos_min, pos_range,
                                               order_qk, order_v);
    qk_kernel<<<NTOK, 256, 0, stream>>>(order_qk, x, qk_pos, tauQ, tauK,
                                        qk_neurons, npos_qk, cm_qk,
                                        pos_min, pos_range, Q, K, acc);
    v_kernel<<<NTOK, 256, 0, stream>>>(order_v, x, v_pos, tauV,
                                       v_neurons, npos_v, cm_v,
                                       pos_min, pos_range, V, acc);
    attn_partial_kernel<<<1152, 128, 0, stream>>>(Q, K, V, pm, pl, po);
    attn_combine_kernel<<<(NROWS * 64) / 256, 256, 0, stream>>>(pm, pl, po, AO);
    proj_kernel<<<NTOK / 4, 256, 0, stream>>>(AO, expand_O, out);
    ploss_kernel<<<1, 1, 0, stream>>>(acc, out + TDf);
}